// Round 15
// baseline (190.364 us; speedup 1.0000x reference)
//
#include <hip/hip_runtime.h>
#include <stdint.h>

typedef short bf16x8 __attribute__((ext_vector_type(8)));
typedef float f32x4  __attribute__((ext_vector_type(4)));

__device__ __forceinline__ unsigned short f2bf(float f) {
    unsigned int u = __float_as_uint(f);
    u += 0x7FFFu + ((u >> 16) & 1u);
    return (unsigned short)(u >> 16);
}
__device__ __forceinline__ float bf2f(unsigned short h) {
    return __uint_as_float(((unsigned int)h) << 16);
}

#define WAVE_ROWS 32

// Single fused dispatch: phase0 fuse-weights | gridbar | phase1 gemm (LDS wcT)
// | gridbar | phase2 gather. Software grid barrier is the guide-sanctioned
// device-scope pattern (threadfence release + device atomicAdd + poll +
// threadfence acquire). Co-residency: 64KB LDS + launch_bounds(512,4)
// (VGPR<=128) -> 2 blocks/CU -> 512 slots >= 391 blocks. Saves 2 launch gaps
// + ramp/drain vs 3 dispatches (R14: ~18us residual overhead).
__global__ __launch_bounds__(512, 4) void fused_all(
    const float* __restrict__ x,
    const float* __restrict__ w1, const float* __restrict__ b1,
    const float* __restrict__ w2, const float* __restrict__ b2,
    const float* __restrict__ wf, const float* __restrict__ bfv,
    const int* __restrict__ ci,
    unsigned short* __restrict__ wcT, float* __restrict__ cb,
    unsigned short* __restrict__ gbuf,
    float* __restrict__ out, float* __restrict__ maskout,
    int nrows, int ntiles, int nblk, unsigned* __restrict__ bar)
{
    __shared__ uint4 ldsw[4096];   // 64 KB swizzled wcT
    int tid  = threadIdx.x;
    int bid  = blockIdx.x;
    int lane = tid & 63;
    int wid  = tid >> 6;

    // ---------------- phase 0: fuse weights (258 jobs x 128 threads) -------
    {
        int tg = bid * 512 + tid;
        if (tg < 258 * 128) {
            int c   = tg & 127;
            int job = tg >> 7;
            int mat = (job >= 129) ? 1 : 0;
            int kk  = job - mat * 129;
            const float* w = mat ? w2 : w1;
            const float* b = mat ? b2 : b1;
            float acc = 0.f;
            if (kk < 128) {
                #pragma unroll 8
                for (int j = 0; j < 128; ++j) acc += w[kk * 128 + j] * wf[j * 128 + c];
                wcT[mat * 16384 + c * 128 + kk] = f2bf(acc);
            } else {
                #pragma unroll 8
                for (int j = 0; j < 128; ++j) acc += b[j] * wf[j * 128 + c];
                cb[mat * 128 + c] = acc;
            }
        }
    }

    // ---------------- grid barrier 1 ---------------------------------------
    __syncthreads();
    if (tid == 0) {
        __threadfence();                                   // release (wb L2)
        atomicAdd(bar, 1u);
        while (__hip_atomic_load(bar, __ATOMIC_RELAXED, __HIP_MEMORY_SCOPE_AGENT)
               < (unsigned)nblk)
            __builtin_amdgcn_s_sleep(1);
        __threadfence();                                   // acquire (inv)
    }
    __syncthreads();

    // ---------------- phase 1: gemm ----------------------------------------
    {
        int lrow = lane & 15;
        int kg   = lane >> 4;
        int swz  = (lrow & 7) << 4;

        const uint4* w4 = (const uint4*)wcT;
        #pragma unroll
        for (int i = 0; i < 8; ++i) {
            int idx = tid + i * 512;
            uint4 v = w4[idx];
            int b   = idx << 4;
            int sb  = b ^ (((b >> 8) & 7) << 4);
            ldsw[sb >> 4] = v;
        }
        __syncthreads();
        const char* lbase = (const char*)ldsw;

        for (int tile = bid; tile < ntiles; tile += nblk) {
            int r0 = tile * 256 + wid * WAVE_ROWS;
            if (r0 >= nrows) continue;

            bf16x8 xf[2][4];
            #pragma unroll
            for (int t = 0; t < 2; ++t) {
                int row = r0 + t * 16 + lrow;
                bool v  = row < nrows;
                #pragma unroll
                for (int ks = 0; ks < 4; ++ks) {
                    int k0 = ks * 32 + kg * 8;
                    float4 p0 = v ? *(const float4*)(x + (size_t)row * 128 + k0)     : float4{0,0,0,0};
                    float4 p1 = v ? *(const float4*)(x + (size_t)row * 128 + k0 + 4) : float4{0,0,0,0};
                    bf16x8 f;
                    f[0] = (short)f2bf(p0.x); f[1] = (short)f2bf(p0.y);
                    f[2] = (short)f2bf(p0.z); f[3] = (short)f2bf(p0.w);
                    f[4] = (short)f2bf(p1.x); f[5] = (short)f2bf(p1.y);
                    f[6] = (short)f2bf(p1.z); f[7] = (short)f2bf(p1.w);
                    xf[t][ks] = f;
                }
            }

            #pragma unroll
            for (int mat = 0; mat < 2; ++mat) {
                unsigned short* gm = gbuf + (size_t)mat * nrows * 128;
                int mb = mat * 32768;
                #pragma unroll 2
                for (int c = 0; c < 8; ++c) {
                    int colb = mb + (c * 16 + lrow) * 256 + kg * 16;
                    bf16x8 wfr[4];
                    #pragma unroll
                    for (int ks = 0; ks < 4; ++ks)
                        wfr[ks] = *(const bf16x8*)(lbase + ((colb + ks * 64) ^ swz));
                    f32x4 acc[2];
                    #pragma unroll
                    for (int t = 0; t < 2; ++t) acc[t] = f32x4{0,0,0,0};
                    #pragma unroll
                    for (int ks = 0; ks < 4; ++ks) {
                        #pragma unroll
                        for (int t = 0; t < 2; ++t)
                            acc[t] = __builtin_amdgcn_mfma_f32_16x16x32_bf16(wfr[ks], xf[t][ks], acc[t], 0,0,0);
                    }
                    float4 bias = *(const float4*)(cb + mat * 128 + c * 16 + kg * 4);
                    #pragma unroll
                    for (int t = 0; t < 2; ++t) {
                        int xrow = r0 + t * 16 + lrow;
                        if (xrow < nrows) {
                            ushort4 o;
                            o.x = f2bf(acc[t][0] + bias.x); o.y = f2bf(acc[t][1] + bias.y);
                            o.z = f2bf(acc[t][2] + bias.z); o.w = f2bf(acc[t][3] + bias.w);
                            *(ushort4*)(gm + (size_t)xrow * 128 + c * 16 + kg * 4) = o;
                        }
                    }
                }
            }
        }
    }

    // ---------------- grid barrier 2 ---------------------------------------
    __syncthreads();
    if (tid == 0) {
        __threadfence();
        atomicAdd(bar, 1u);
        while (__hip_atomic_load(bar, __ATOMIC_RELAXED, __HIP_MEMORY_SCOPE_AGENT)
               < (unsigned)(2 * nblk))
            __builtin_amdgcn_s_sleep(1);
        __threadfence();
    }
    __syncthreads();

    // ---------------- phase 2: gather (grid-strided node-waves) ------------
    {
        const unsigned short* g1 = gbuf;
        const unsigned short* g2 = gbuf + (size_t)nrows * 128;
        int half = lane >> 5;
        int hl   = lane & 31;
        int d4   = hl * 4;
        float4 bfd = *(const float4*)(bfv + d4);

        for (int n = bid * 8 + wid; n < nrows; n += nblk * 8) {
            int civ = ci[n * 8 + (lane & 7)];
            unsigned long long bal = __ballot(civ == -1);
            int cnt = __popcll(bal & 0xFFull);
            int deg = (cnt == 8) ? 0 : (7 - cnt);     // wave-uniform
            bool two = (deg >= 2);

            uint2 va[4], vb[4];
            #pragma unroll
            for (int c = 0; c < 4; ++c) {
                va[c] = uint2{0u, 0u};
                vb[c] = uint2{0u, 0u};
                if (2 * c < deg) {                    // wave-uniform skip
                    int r  = 2 * c + half;
                    int i0 = __shfl(civ, r);
                    int i1 = __shfl(civ, r + 1);
                    bool m = (r < deg);
                    va[c] = m          ? *(const uint2*)(g1 + (size_t)i0 * 128 + d4) : uint2{0u, 0u};
                    vb[c] = (m && two) ? *(const uint2*)(g2 + (size_t)i1 * 128 + d4) : uint2{0u, 0u};
                }
            }

            size_t base = (size_t)n * 896;
            #pragma unroll
            for (int c = 0; c < 4; ++c) {
                f32x4 o;
                o[0] = bfd.x + bf2f((unsigned short)(va[c].x & 0xFFFFu)) + bf2f((unsigned short)(vb[c].x & 0xFFFFu));
                o[1] = bfd.y + bf2f((unsigned short)(va[c].x >> 16))     + bf2f((unsigned short)(vb[c].x >> 16));
                o[2] = bfd.z + bf2f((unsigned short)(va[c].y & 0xFFFFu)) + bf2f((unsigned short)(vb[c].y & 0xFFFFu));
                o[3] = bfd.w + bf2f((unsigned short)(va[c].y >> 16))     + bf2f((unsigned short)(vb[c].y >> 16));
                if (c < 3)
                    __builtin_nontemporal_store(o, (f32x4*)(out + base + c * 256 + lane * 4));
                else if (half == 0)
                    __builtin_nontemporal_store(o, (f32x4*)(out + base + 768 + hl * 4));
            }
            if (lane < 7)
                __builtin_nontemporal_store((lane < deg) ? 1.0f : 0.0f, maskout + n * 7 + lane);
        }
    }
}

extern "C" void kernel_launch(void* const* d_in, const int* in_sizes, int n_in,
                              void* d_out, int out_size, void* d_ws, size_t ws_size,
                              hipStream_t stream) {
    const float* x   = (const float*)d_in[0];
    const float* w1  = (const float*)d_in[1];
    const float* b1  = (const float*)d_in[2];
    const float* w2  = (const float*)d_in[3];
    const float* b2  = (const float*)d_in[4];
    const float* wf  = (const float*)d_in[5];
    const float* bfv = (const float*)d_in[6];
    const int*   ci  = (const int*)d_in[7];

    int nrows  = in_sizes[0] / 128;
    int ntiles = (nrows + 255) / 256;
    int nblk   = ntiles < 448 ? ntiles : 448;   // 391 for N=100k; capacity 512

    // ws layout: g | wcT | cb | bar
    size_t gbytes = (size_t)2 * nrows * 128 * 2;
    unsigned short* g   = (unsigned short*)d_ws;
    unsigned short* wcT = (unsigned short*)((char*)d_ws + ((gbytes + 255) & ~(size_t)255));
    float*          cb  = (float*)((char*)wcT + 2 * 128 * 128 * 2);
    unsigned*       bar = (unsigned*)((char*)cb + 1024);

    hipMemsetAsync(bar, 0, 256, stream);        // barrier counter = 0 each call

    int rows = nrows * 7;
    float* out = (float*)d_out;
    fused_all<<<nblk, 512, 0, stream>>>(x, w1, b1, w2, b2, wf, bfv, ci,
                                        wcT, cb, g, out, out + (size_t)rows * 128,
                                        nrows, ntiles, nblk, bar);
}

// Round 16
// 108.421 us; speedup vs baseline: 1.7558x; 1.7558x over previous
//
#include <hip/hip_runtime.h>
#include <stdint.h>

typedef short bf16x8 __attribute__((ext_vector_type(8)));
typedef float f32x4  __attribute__((ext_vector_type(4)));

__device__ __forceinline__ unsigned short f2bf(float f) {
    unsigned int u = __float_as_uint(f);
    u += 0x7FFFu + ((u >> 16) & 1u);
    return (unsigned short)(u >> 16);
}
__device__ __forceinline__ float bf2f(unsigned short h) {
    return __uint_as_float(((unsigned int)h) << 16);
}

// ---- kernel A: fold W1f = w1@wf, W2f = w2@wf (store transposed bf16), cb = b@wf ----
__global__ void fuse_weights(const float* __restrict__ w1, const float* __restrict__ b1,
                             const float* __restrict__ w2, const float* __restrict__ b2,
                             const float* __restrict__ wf,
                             unsigned short* __restrict__ wcT,  // [2][128 cols][128 k]
                             float* __restrict__ cb)            // [2][128]
{
    int mat = blockIdx.x / 129;
    int kk  = blockIdx.x % 129;
    int c   = threadIdx.x;
    const float* w = (mat == 0) ? w1 : w2;
    const float* b = (mat == 0) ? b1 : b2;
    float acc = 0.f;
    if (kk < 128) {
        #pragma unroll 8
        for (int j = 0; j < 128; ++j) acc += w[kk * 128 + j] * wf[j * 128 + c];
        wcT[mat * 16384 + c * 128 + kk] = f2bf(acc);
    } else {
        #pragma unroll 8
        for (int j = 0; j < 128; ++j) acc += b[j] * wf[j * 128 + c];
        cb[mat * 128 + c] = acc;
    }
}

// ---- kernel B: g[mat] = x @ Wc[mat] + cb[mat] -> bf16 [2][nrows][128] ----
// R16: BALANCED grid. 512 blocks (2/CU exactly, LDS-capped), each block owns a
// contiguous ~196-row range -> every CU does ~392 rows (R14: 135 CUs did 512
// rows, 121 did 256 -> 1.3x makespan tail). Same 64KB swizzled-LDS wcT.
__global__ __launch_bounds__(512, 4) void gemm_g(
    const float* __restrict__ x, const unsigned short* __restrict__ wcT,
    const float* __restrict__ cb, unsigned short* __restrict__ g,
    int nrows, int rpb)
{
    __shared__ uint4 ldsw[4096];   // 64 KB: [2 mats][128 cols][128 k] bf16, swizzled

    int tid  = threadIdx.x;
    int lane = tid & 63;
    int wid  = tid >> 6;
    int rbase = blockIdx.x * rpb;
    int rend  = rbase + rpb; if (rend > nrows) rend = nrows;
    int r0   = rbase + wid * 32;
    int lrow = lane & 15;
    int kg   = lane >> 4;
    int swz  = (lrow & 7) << 4;    // wave-constant per lane

    // ---- cooperative LDS fill with XOR swizzle on byte bits 4-6 ----
    const uint4* w4 = (const uint4*)wcT;
    #pragma unroll
    for (int i = 0; i < 8; ++i) {
        int idx = tid + i * 512;               // uint4 index, 0..4095
        uint4 v = w4[idx];
        int b   = idx << 4;                    // byte addr
        int sb  = b ^ (((b >> 8) & 7) << 4);   // (col&7)<<4 swizzle
        ldsw[sb >> 4] = v;
    }

    // x fragment loads (overlap with LDS fill latency); per-row guards
    bf16x8 xf[2][4];   // [rowtile][kstep]
    #pragma unroll
    for (int t = 0; t < 2; ++t) {
        int row = r0 + t * 16 + lrow;
        bool v  = row < rend;
        #pragma unroll
        for (int ks = 0; ks < 4; ++ks) {
            int k0 = ks * 32 + kg * 8;
            float4 p0 = v ? *(const float4*)(x + (size_t)row * 128 + k0)     : float4{0,0,0,0};
            float4 p1 = v ? *(const float4*)(x + (size_t)row * 128 + k0 + 4) : float4{0,0,0,0};
            bf16x8 f;
            f[0] = (short)f2bf(p0.x); f[1] = (short)f2bf(p0.y);
            f[2] = (short)f2bf(p0.z); f[3] = (short)f2bf(p0.w);
            f[4] = (short)f2bf(p1.x); f[5] = (short)f2bf(p1.y);
            f[6] = (short)f2bf(p1.z); f[7] = (short)f2bf(p1.w);
            xf[t][ks] = f;
        }
    }

    __syncthreads();
    if (r0 >= rend) return;

    const char* lbase = (const char*)ldsw;
    #pragma unroll
    for (int mat = 0; mat < 2; ++mat) {
        unsigned short* gm = g + (size_t)mat * nrows * 128;
        int mb = mat * 32768;
        #pragma unroll 2
        for (int c = 0; c < 8; ++c) {
            int colb = mb + (c * 16 + lrow) * 256 + kg * 16;
            bf16x8 wfr[4];
            #pragma unroll
            for (int ks = 0; ks < 4; ++ks)
                wfr[ks] = *(const bf16x8*)(lbase + ((colb + ks * 64) ^ swz));
            f32x4 acc[2];
            #pragma unroll
            for (int t = 0; t < 2; ++t) acc[t] = f32x4{0,0,0,0};
            #pragma unroll
            for (int ks = 0; ks < 4; ++ks) {
                #pragma unroll
                for (int t = 0; t < 2; ++t)
                    acc[t] = __builtin_amdgcn_mfma_f32_16x16x32_bf16(wfr[ks], xf[t][ks], acc[t], 0,0,0);
            }
            float4 bias = *(const float4*)(cb + mat * 128 + c * 16 + kg * 4);
            #pragma unroll
            for (int t = 0; t < 2; ++t) {
                int xrow = r0 + t * 16 + lrow;
                if (xrow < rend) {
                    ushort4 o;
                    o.x = f2bf(acc[t][0] + bias.x); o.y = f2bf(acc[t][1] + bias.y);
                    o.z = f2bf(acc[t][2] + bias.z); o.w = f2bf(acc[t][3] + bias.w);
                    *(ushort4*)(gm + (size_t)xrow * 128 + c * 16 + kg * 4) = o;
                }
            }
        }
    }
}

// ---- kernel C (R14 form): one wave per node, chunked f32x4 nt stores ----
__global__ __launch_bounds__(256) void gather_out(
    const int* __restrict__ ci, const unsigned short* __restrict__ g,
    const float* __restrict__ bfv, float* __restrict__ out,
    float* __restrict__ maskout, int nnodes)
{
    int n    = (int)((blockIdx.x * blockDim.x + threadIdx.x) >> 6);
    int lane = threadIdx.x & 63;
    if (n >= nnodes) return;

    int civ = ci[n * 8 + (lane & 7)];
    unsigned long long bal = __ballot(civ == -1);
    int cnt = __popcll(bal & 0xFFull);
    int deg = (cnt == 8) ? 0 : (7 - cnt);     // wave-uniform

    int half = lane >> 5;
    int hl   = lane & 31;
    int d4   = hl * 4;                        // 4 dims per lane
    float4 bfd = *(const float4*)(bfv + d4);
    const unsigned short* g1 = g;
    const unsigned short* g2 = g + (size_t)nnodes * 128;
    bool two = (deg >= 2);

    // ---- load phase: all needed rows in flight before any consumption ----
    uint2 va[4], vb[4];
    #pragma unroll
    for (int c = 0; c < 4; ++c) {
        va[c] = uint2{0u, 0u};
        vb[c] = uint2{0u, 0u};
        if (2 * c < deg) {                    // wave-uniform skip
            int r  = 2 * c + half;            // row 0..7 (row 7 always masked)
            int i0 = __shfl(civ, r);
            int i1 = __shfl(civ, r + 1);
            bool m = (r < deg);
            va[c] = m          ? *(const uint2*)(g1 + (size_t)i0 * 128 + d4) : uint2{0u, 0u};
            vb[c] = (m && two) ? *(const uint2*)(g2 + (size_t)i1 * 128 + d4) : uint2{0u, 0u};
        }
    }

    // ---- consume + store (branch-free adds; zero bits are exact no-ops) ----
    size_t base = (size_t)n * 896;            // 7*128
    #pragma unroll
    for (int c = 0; c < 4; ++c) {
        f32x4 o;
        o[0] = bfd.x + bf2f((unsigned short)(va[c].x & 0xFFFFu)) + bf2f((unsigned short)(vb[c].x & 0xFFFFu));
        o[1] = bfd.y + bf2f((unsigned short)(va[c].x >> 16))     + bf2f((unsigned short)(vb[c].x >> 16));
        o[2] = bfd.z + bf2f((unsigned short)(va[c].y & 0xFFFFu)) + bf2f((unsigned short)(vb[c].y & 0xFFFFu));
        o[3] = bfd.w + bf2f((unsigned short)(va[c].y >> 16))     + bf2f((unsigned short)(vb[c].y >> 16));
        if (c < 3)
            __builtin_nontemporal_store(o, (f32x4*)(out + base + c * 256 + lane * 4));
        else if (half == 0)
            __builtin_nontemporal_store(o, (f32x4*)(out + base + 768 + hl * 4));
    }
    if (lane < 7)
        __builtin_nontemporal_store((lane < deg) ? 1.0f : 0.0f, maskout + n * 7 + lane);
}

extern "C" void kernel_launch(void* const* d_in, const int* in_sizes, int n_in,
                              void* d_out, int out_size, void* d_ws, size_t ws_size,
                              hipStream_t stream) {
    const float* x   = (const float*)d_in[0];
    const float* w1  = (const float*)d_in[1];
    const float* b1  = (const float*)d_in[2];
    const float* w2  = (const float*)d_in[3];
    const float* b2  = (const float*)d_in[4];
    const float* wf  = (const float*)d_in[5];
    const float* bfv = (const float*)d_in[6];
    const int*   ci  = (const int*)d_in[7];

    int nrows = in_sizes[0] / 128;

    size_t gbytes = (size_t)2 * nrows * 128 * 2;
    unsigned short* g   = (unsigned short*)d_ws;
    unsigned short* wcT = (unsigned short*)((char*)d_ws + ((gbytes + 255) & ~(size_t)255));
    float*          cb  = (float*)((char*)wcT + 2 * 128 * 128 * 2);

    fuse_weights<<<2 * 129, 128, 0, stream>>>(w1, b1, w2, b2, wf, wcT, cb);

    int nblkB = 512;                              // 2 blocks/CU exactly
    int rpb   = (nrows + nblkB - 1) / nblkB;      // 196 rows/block @ N=100k
    gemm_g<<<nblkB, 512, 0, stream>>>(x, wcT, cb, g, nrows, rpb);

    int rows = nrows * 7;
    int cblk = (nrows * 64 + 255) / 256;
    float* out = (float*)d_out;
    gather_out<<<cblk, 256, 0, stream>>>(ci, g, bfv, out, out + (size_t)rows * 128, nrows);
}